// Round 1
// baseline (2014.113 us; speedup 1.0000x reference)
//
#include <hip/hip_runtime.h>

#define B_   2
#define L_   1024
#define T_   2048      // B_*L_
#define DM   2048
#define DI   4096
#define E2   8192
#define NS   16
#define RK   128
#define EX   160       // RK + 2*NS
#define MB(x) ((size_t)(x) << 20)

__device__ __forceinline__ float sigmoidf_(float x) { return 1.f / (1.f + __expf(-x)); }

// ---------------------------------------------------------------------------
// Generic fp32 BT-GEMM: C[m][n] = sum_k A[m*lda+k] * B[n*ldb+k]
// tiles 128x128, BK=8, 256 threads, 8x8 per thread. M,N multiples of 128.
// ---------------------------------------------------------------------------
__global__ __launch_bounds__(256)
void gemm_bt_128(const float* __restrict__ A, const float* __restrict__ B,
                 float* __restrict__ C, int K, int lda, int ldb, int ldc)
{
    __shared__ float As[8][132];
    __shared__ float Bs[8][132];
    const int bm  = blockIdx.y * 128;
    const int bn  = blockIdx.x * 128;
    const int tid = threadIdx.x;
    const int tr  = tid >> 4;          // 0..15
    const int tc  = tid & 15;          // 0..15
    const int lr  = tid >> 1;          // 0..127
    const int lk  = (tid & 1) * 4;     // 0 or 4
    const float* Ap = A + (size_t)(bm + lr) * lda + lk;
    const float* Bp = B + (size_t)(bn + lr) * ldb + lk;
    float acc[8][8] = {};
    for (int k0 = 0; k0 < K; k0 += 8) {
        float4 a4 = *(const float4*)(Ap + k0);
        float4 b4 = *(const float4*)(Bp + k0);
        __syncthreads();
        As[lk+0][lr] = a4.x; As[lk+1][lr] = a4.y; As[lk+2][lr] = a4.z; As[lk+3][lr] = a4.w;
        Bs[lk+0][lr] = b4.x; Bs[lk+1][lr] = b4.y; Bs[lk+2][lr] = b4.z; Bs[lk+3][lr] = b4.w;
        __syncthreads();
        #pragma unroll
        for (int k = 0; k < 8; ++k) {
            float af[8], bf[8];
            *(float4*)&af[0] = *(const float4*)&As[k][tr*8];
            *(float4*)&af[4] = *(const float4*)&As[k][tr*8+4];
            *(float4*)&bf[0] = *(const float4*)&Bs[k][tc*8];
            *(float4*)&bf[4] = *(const float4*)&Bs[k][tc*8+4];
            #pragma unroll
            for (int i = 0; i < 8; ++i)
                #pragma unroll
                for (int j = 0; j < 8; ++j)
                    acc[i][j] = fmaf(af[i], bf[j], acc[i][j]);
        }
    }
    #pragma unroll
    for (int i = 0; i < 8; ++i) {
        float4 v0 = make_float4(acc[i][0], acc[i][1], acc[i][2], acc[i][3]);
        float4 v1 = make_float4(acc[i][4], acc[i][5], acc[i][6], acc[i][7]);
        float* cp = C + (size_t)(bm + tr*8 + i) * ldc + bn + tc*8;
        *(float4*)cp       = v0;
        *(float4*)(cp + 4) = v1;
    }
}

// ---------------------------------------------------------------------------
// x_proj: C[t][e] += sum_k xc[t][k] * W_x[e][k];  M=2048, N=160, K=4096
// split-K (8 chunks of 512) + atomicAdd; tile 128x32, BK=16, 8x2 per thread.
// grid (5, 16, 8)
// ---------------------------------------------------------------------------
__global__ __launch_bounds__(256)
void gemm_xproj(const float* __restrict__ A, const float* __restrict__ B,
                float* __restrict__ C)
{
    __shared__ float As[16][132];
    __shared__ float Bs[16][36];
    const int bn    = blockIdx.x * 32;
    const int bm    = blockIdx.y * 128;
    const int kbase = blockIdx.z * 512;
    const int tid = threadIdx.x;
    const int tr  = tid >> 4;
    const int tc  = tid & 15;
    const int ar  = tid >> 2;          // 0..63
    const int ak  = (tid & 3) * 4;     // 0,4,8,12
    float acc[8][2] = {};
    for (int kc = 0; kc < 512; kc += 16) {
        const int k0 = kbase + kc;
        float4 a0 = *(const float4*)(A + (size_t)(bm + ar) * DI + k0 + ak);
        float4 a1 = *(const float4*)(A + (size_t)(bm + ar + 64) * DI + k0 + ak);
        float4 b0 = {0,0,0,0};
        if (tid < 128) b0 = *(const float4*)(B + (size_t)(bn + (tid >> 2)) * DI + k0 + ak);
        __syncthreads();
        As[ak+0][ar] = a0.x; As[ak+1][ar] = a0.y; As[ak+2][ar] = a0.z; As[ak+3][ar] = a0.w;
        As[ak+0][ar+64] = a1.x; As[ak+1][ar+64] = a1.y; As[ak+2][ar+64] = a1.z; As[ak+3][ar+64] = a1.w;
        if (tid < 128) {
            const int br = tid >> 2;
            Bs[ak+0][br] = b0.x; Bs[ak+1][br] = b0.y; Bs[ak+2][br] = b0.z; Bs[ak+3][br] = b0.w;
        }
        __syncthreads();
        #pragma unroll
        for (int k = 0; k < 16; ++k) {
            float af[8];
            *(float4*)&af[0] = *(const float4*)&As[k][tr*8];
            *(float4*)&af[4] = *(const float4*)&As[k][tr*8+4];
            const float bf0 = Bs[k][tc*2], bf1 = Bs[k][tc*2+1];
            #pragma unroll
            for (int i = 0; i < 8; ++i) {
                acc[i][0] = fmaf(af[i], bf0, acc[i][0]);
                acc[i][1] = fmaf(af[i], bf1, acc[i][1]);
            }
        }
    }
    #pragma unroll
    for (int i = 0; i < 8; ++i) {
        atomicAdd(&C[(size_t)(bm + tr*8 + i) * EX + bn + tc*2 + 0], acc[i][0]);
        atomicAdd(&C[(size_t)(bm + tr*8 + i) * EX + bn + tc*2 + 1], acc[i][1]);
    }
}

// ---------------------------------------------------------------------------
// causal depthwise conv (d_conv=4) + SiLU.  x = first half of xz (token-major)
// one thread per (t, 4 channels)
// ---------------------------------------------------------------------------
__global__ __launch_bounds__(256)
void conv_silu(const float* __restrict__ xz, const float* __restrict__ cw,
               const float* __restrict__ cb, float* __restrict__ xc)
{
    const int g   = blockIdx.x * 256 + threadIdx.x;
    const int nd4 = DI / 4;
    const int t   = g / nd4;
    const int d   = (g % nd4) * 4;
    const int l   = t & (L_ - 1);
    float w[4][4];
    #pragma unroll
    for (int c2 = 0; c2 < 4; ++c2) {
        float4 w4 = *(const float4*)(cw + (size_t)(d + c2) * 4);
        w[c2][0] = w4.x; w[c2][1] = w4.y; w[c2][2] = w4.z; w[c2][3] = w4.w;
    }
    float4 acc = *(const float4*)(cb + d);
    #pragma unroll
    for (int j = 0; j < 4; ++j) {
        const int lj = l + j - 3;
        if (lj >= 0) {
            const float4 x4 = *(const float4*)(xz + (size_t)(t + j - 3) * E2 + d);
            acc.x = fmaf(x4.x, w[0][j], acc.x);
            acc.y = fmaf(x4.y, w[1][j], acc.y);
            acc.z = fmaf(x4.z, w[2][j], acc.z);
            acc.w = fmaf(x4.w, w[3][j], acc.w);
        }
    }
    acc.x *= sigmoidf_(acc.x); acc.y *= sigmoidf_(acc.y);
    acc.z *= sigmoidf_(acc.z); acc.w *= sigmoidf_(acc.w);
    *(float4*)(xc + (size_t)t * DI + d) = acc;
}

// ---------------------------------------------------------------------------
// selective scan, (d,n)-parallel: block = 16 channels x 16 states, b fixed.
// LDS-chunked (64 steps) staging of dt/u/B/C/z. Fuses softplus, D*u, silu(z).
// grid 512 (= B_ * DI/16)
// ---------------------------------------------------------------------------
__global__ __launch_bounds__(256)
void scan_kernel(const float* __restrict__ u_in,   // xc  [T][DI]
                 const float* __restrict__ xdbl,   // [T][EX]
                 const float* __restrict__ draw,   // raw delta [T][DI]
                 const float* __restrict__ xz,     // [T][E2], z at col DI+d
                 const float* __restrict__ dt_bias,
                 const float* __restrict__ A_log,  // [DI][NS]
                 const float* __restrict__ Dvec,
                 float* __restrict__ y)            // [T][DI]
{
    __shared__ float sdt[64][16];
    __shared__ float su [64][16];
    __shared__ float sB [64][16];
    __shared__ float sC [64][16];
    __shared__ float sz [64][16];
    const int blk = blockIdx.x;
    const int b   = blk >> 8;
    const int d0  = (blk & 255) * 16;
    const int tid = threadIdx.x;
    const int ch  = tid >> 4;
    const int n   = tid & 15;
    const int d   = d0 + ch;
    const float a    = -__expf(A_log[(size_t)d * NS + n]);
    const float bias = dt_bias[d];
    const float Dd   = Dvec[d];
    const int li = tid >> 4;
    const int lc = tid & 15;
    float s = 0.f;
    for (int c = 0; c < L_ / 64; ++c) {
        const int t0 = b * L_ + c * 64;
        __syncthreads();
        #pragma unroll
        for (int p = 0; p < 4; ++p) {
            const int i = li + p * 16;
            const size_t trow = (size_t)(t0 + i);
            sdt[i][lc] = draw[trow * DI + d0 + lc];
            su [i][lc] = u_in[trow * DI + d0 + lc];
            sB [i][lc] = xdbl[trow * EX + RK + lc];
            sC [i][lc] = xdbl[trow * EX + RK + NS + lc];
            sz [i][lc] = xz  [trow * E2 + DI + d0 + lc];
        }
        __syncthreads();
        #pragma unroll 4
        for (int i = 0; i < 64; ++i) {
            const float x  = sdt[i][ch] + bias;
            const float dt = fmaxf(x, 0.f) + __logf(1.f + __expf(-fabsf(x)));
            const float u  = su[i][ch];
            const float dA = __expf(dt * a);
            s = fmaf(s, dA, dt * u * sB[i][n]);
            float pc = s * sC[i][n];
            pc += __shfl_xor(pc, 8);
            pc += __shfl_xor(pc, 4);
            pc += __shfl_xor(pc, 2);
            pc += __shfl_xor(pc, 1);
            if (n == 0) {
                const float zv = sz[i][ch];
                const float yv = (pc + Dd * u) * (zv * sigmoidf_(zv));
                y[(size_t)(t0 + i) * DI + d] = yv;
            }
        }
    }
}

// ---------------------------------------------------------------------------
// in-place normalized FWHT over d_inner=4096 per token (replaces y @ H)
// ---------------------------------------------------------------------------
__global__ __launch_bounds__(256)
void fwht_kernel(float* __restrict__ y)
{
    __shared__ float ls[4096];
    float* row = y + (size_t)blockIdx.x * DI;
    for (int i = threadIdx.x; i < 4096; i += 256) ls[i] = row[i];
    __syncthreads();
    for (int st = 0; st < 12; ++st) {
        const int stride = 1 << st;
        for (int k = threadIdx.x; k < 2048; k += 256) {
            const int i = ((k >> st) << (st + 1)) | (k & (stride - 1));
            const int j = i | stride;
            const float a = ls[i], b = ls[j];
            ls[i] = a + b; ls[j] = a - b;
        }
        __syncthreads();
    }
    const float sc = 1.0f / 64.0f;   // 1/sqrt(4096)
    for (int i = threadIdx.x; i < 4096; i += 256) row[i] = ls[i] * sc;
}

// ---------------------------------------------------------------------------
extern "C" void kernel_launch(void* const* d_in, const int* in_sizes, int n_in,
                              void* d_out, int out_size, void* d_ws, size_t ws_size,
                              hipStream_t stream)
{
    const float* hidden  = (const float*)d_in[0];
    const float* W_in    = (const float*)d_in[1];
    const float* conv_w  = (const float*)d_in[2];
    const float* conv_b  = (const float*)d_in[3];
    const float* W_x     = (const float*)d_in[4];
    const float* W_dt    = (const float*)d_in[5];
    const float* dt_bias = (const float*)d_in[6];
    const float* A_log   = (const float*)d_in[7];
    const float* Dvec    = (const float*)d_in[8];
    const float* W_out   = (const float*)d_in[9];
    float* out = (float*)d_out;

    char* ws = (char*)d_ws;
    float* xz   = (float*)(ws);            // T_*E2*4  = 64 MB
    float* xc   = (float*)(ws + MB(64));   // T_*DI*4  = 32 MB
    float* xdbl = (float*)(ws + MB(96));   // T_*EX*4  = 1.25 MB
    float* draw = (float*)(ws + MB(98));   // T_*DI*4  = 32 MB
    float* ybuf = (float*)(ws + MB(130));  // T_*DI*4  = 32 MB

    const dim3 blk(256);

    // 1) in_proj: xz[t][e] = hidden[t][:] . W_in[e][:]
    gemm_bt_128<<<dim3(E2/128, T_/128), blk, 0, stream>>>(hidden, W_in, xz, DM, DM, DM, E2);

    // 2) depthwise causal conv + SiLU -> xc
    conv_silu<<<dim3((T_ * (DI/4)) / 256), blk, 0, stream>>>(xz, conv_w, conv_b, xc);

    // 3) x_proj: xdbl[t][e] = xc[t][:] . W_x[e][:]  (split-K, atomic)
    hipMemsetAsync(xdbl, 0, (size_t)T_ * EX * sizeof(float), stream);
    gemm_xproj<<<dim3(5, 16, 8), blk, 0, stream>>>(xc, W_x, xdbl);

    // 4) dt_proj: draw[t][d] = xdbl[t][0:128] . W_dt[d][:]
    gemm_bt_128<<<dim3(DI/128, T_/128), blk, 0, stream>>>(xdbl, W_dt, draw, RK, EX, RK, DI);

    // 5) selective scan + D*u + silu(z) gate -> ybuf
    scan_kernel<<<dim3(512), blk, 0, stream>>>(xc, xdbl, draw, xz, dt_bias, A_log, Dvec, ybuf);

    // 6) Hadamard transform (in place, normalized)
    fwht_kernel<<<dim3(T_), blk, 0, stream>>>(ybuf);

    // 7) out_proj -> d_out
    gemm_bt_128<<<dim3(DM/128, T_/128), blk, 0, stream>>>(ybuf, W_out, out, DI, DI, DI, DM);
}

// Round 3
// 989.575 us; speedup vs baseline: 2.0353x; 2.0353x over previous
//
#include <hip/hip_runtime.h>

#define B_   2
#define L_   1024
#define T_   2048      // B_*L_
#define DM   2048
#define DI   4096
#define E2   8192
#define NS   16
#define RK   128
#define EX   160       // RK + 2*NS
#define MB(x) ((size_t)(x) << 20)

typedef __bf16 bf16x8 __attribute__((ext_vector_type(8)));
typedef float  f32x4  __attribute__((ext_vector_type(4)));

__device__ __forceinline__ float sigmoidf_(float x) { return 1.f / (1.f + __expf(-x)); }

__device__ __forceinline__ unsigned short bf_rne(float f) {
    unsigned int u = __float_as_uint(f);
    unsigned int r = u + 0x7fffu + ((u >> 16) & 1u);
    return (unsigned short)(r >> 16);
}
__device__ __forceinline__ float bf_to_f(unsigned short h) {
    return __uint_as_float(((unsigned int)h) << 16);
}

// ---------------------------------------------------------------------------
// fp32 -> bf16 hi/lo split (RNE both): x ~= hi + lo, rel err ~2^-18
// ---------------------------------------------------------------------------
__global__ __launch_bounds__(256)
void split_bf16(const float* __restrict__ x, unsigned short* __restrict__ h,
                unsigned short* __restrict__ l, int n4)
{
    const int i = blockIdx.x * 256 + threadIdx.x;
    if (i >= n4) return;
    const float4 v = ((const float4*)x)[i];
    ushort4 hv, lv;
    hv.x = bf_rne(v.x); lv.x = bf_rne(v.x - bf_to_f(hv.x));
    hv.y = bf_rne(v.y); lv.y = bf_rne(v.y - bf_to_f(hv.y));
    hv.z = bf_rne(v.z); lv.z = bf_rne(v.z - bf_to_f(hv.z));
    hv.w = bf_rne(v.w); lv.w = bf_rne(v.w - bf_to_f(hv.w));
    ((ushort4*)h)[i] = hv;
    ((ushort4*)l)[i] = lv;
}

// ---------------------------------------------------------------------------
// bf16x3 split-precision BT-GEMM: C[m][n] = sum_k A[m][k]*B[n][k], fp32 acc.
// C = Ah.Bh + Ah.Bl + Al.Bh  (lo*lo dropped, rel err ~2^-18).
// m97 structure: 128x128 tile, BK=32, 4 waves, global_load_lds width-16,
// mfma_f32_16x16x32_bf16, 2 barriers/K-step.  M,N multiples of 128, K of 32.
// ---------------------------------------------------------------------------
__global__ __launch_bounds__(256)
void gemm_bf16x3(const unsigned short* __restrict__ Ah, const unsigned short* __restrict__ Al,
                 const unsigned short* __restrict__ Bh, const unsigned short* __restrict__ Bl,
                 float* __restrict__ C, int K, int lda, int ldb, int ldc)
{
    __shared__ unsigned short lsAh[4096], lsAl[4096], lsBh[4096], lsBl[4096];
    const int bm   = blockIdx.y * 128;
    const int bn   = blockIdx.x * 128;
    const int tid  = threadIdx.x;
    const int lane = tid & 63;
    const int wv   = tid >> 6;
    const int wr   = (wv >> 1) * 64;     // wave row offset in tile
    const int wc   = (wv & 1) * 64;      // wave col offset in tile
    const int grow = lane >> 2;          // staging: row within 16-row chunk
    const int gcol = (lane & 3) * 8;     // staging: col (8 bf16 = 16B)
    const int fr   = lane & 15;          // frag row (A) / col (B,D)
    const int fk   = (lane >> 4) * 8;    // frag k offset

    f32x4 acc[4][4] = {};

    for (int k0 = 0; k0 < K; k0 += 32) {
        __syncthreads();
        #pragma unroll
        for (int is = 0; is < 2; ++is) {
            const int c = is * 4 + wv;                       // chunk 0..7 (16 rows each)
            const size_t ao = (size_t)(bm + c * 16 + grow) * lda + k0 + gcol;
            const size_t bo = (size_t)(bn + c * 16 + grow) * ldb + k0 + gcol;
            __builtin_amdgcn_global_load_lds((const __attribute__((address_space(1))) void*)(Ah + ao),
                (__attribute__((address_space(3))) void*)(lsAh + c * 512), 16, 0, 0);
            __builtin_amdgcn_global_load_lds((const __attribute__((address_space(1))) void*)(Al + ao),
                (__attribute__((address_space(3))) void*)(lsAl + c * 512), 16, 0, 0);
            __builtin_amdgcn_global_load_lds((const __attribute__((address_space(1))) void*)(Bh + bo),
                (__attribute__((address_space(3))) void*)(lsBh + c * 512), 16, 0, 0);
            __builtin_amdgcn_global_load_lds((const __attribute__((address_space(1))) void*)(Bl + bo),
                (__attribute__((address_space(3))) void*)(lsBl + c * 512), 16, 0, 0);
        }
        __syncthreads();

        bf16x8 ah[4], al[4], bh[4], bl[4];
        #pragma unroll
        for (int m = 0; m < 4; ++m) {
            const int ra = (wr + m * 16 + fr) * 32 + fk;
            ah[m] = *(const bf16x8*)(lsAh + ra);
            al[m] = *(const bf16x8*)(lsAl + ra);
        }
        #pragma unroll
        for (int n = 0; n < 4; ++n) {
            const int rb = (wc + n * 16 + fr) * 32 + fk;
            bh[n] = *(const bf16x8*)(lsBh + rb);
            bl[n] = *(const bf16x8*)(lsBl + rb);
        }
        #pragma unroll
        for (int m = 0; m < 4; ++m)
            #pragma unroll
            for (int n = 0; n < 4; ++n) {
                acc[m][n] = __builtin_amdgcn_mfma_f32_16x16x32_bf16(ah[m], bh[n], acc[m][n], 0, 0, 0);
                acc[m][n] = __builtin_amdgcn_mfma_f32_16x16x32_bf16(ah[m], bl[n], acc[m][n], 0, 0, 0);
                acc[m][n] = __builtin_amdgcn_mfma_f32_16x16x32_bf16(al[m], bh[n], acc[m][n], 0, 0, 0);
            }
    }

    #pragma unroll
    for (int m = 0; m < 4; ++m)
        #pragma unroll
        for (int n = 0; n < 4; ++n) {
            float* cp = C + (size_t)(bm + wr + m * 16 + (lane >> 4) * 4) * ldc
                          + bn + wc + n * 16 + fr;
            #pragma unroll
            for (int r = 0; r < 4; ++r) cp[(size_t)r * ldc] = acc[m][n][r];
        }
}

// ---------------------------------------------------------------------------
// x_proj (fp32, skinny N=160): split-K + atomicAdd. grid (5, 16, 8)
// ---------------------------------------------------------------------------
__global__ __launch_bounds__(256)
void gemm_xproj(const float* __restrict__ A, const float* __restrict__ B,
                float* __restrict__ C)
{
    __shared__ float As[16][132];
    __shared__ float Bs[16][36];
    const int bn    = blockIdx.x * 32;
    const int bm    = blockIdx.y * 128;
    const int kbase = blockIdx.z * 512;
    const int tid = threadIdx.x;
    const int tr  = tid >> 4;
    const int tc  = tid & 15;
    const int ar  = tid >> 2;
    const int ak  = (tid & 3) * 4;
    float acc[8][2] = {};
    for (int kc = 0; kc < 512; kc += 16) {
        const int k0 = kbase + kc;
        float4 a0 = *(const float4*)(A + (size_t)(bm + ar) * DI + k0 + ak);
        float4 a1 = *(const float4*)(A + (size_t)(bm + ar + 64) * DI + k0 + ak);
        float4 b0 = {0,0,0,0};
        if (tid < 128) b0 = *(const float4*)(B + (size_t)(bn + (tid >> 2)) * DI + k0 + ak);
        __syncthreads();
        As[ak+0][ar] = a0.x; As[ak+1][ar] = a0.y; As[ak+2][ar] = a0.z; As[ak+3][ar] = a0.w;
        As[ak+0][ar+64] = a1.x; As[ak+1][ar+64] = a1.y; As[ak+2][ar+64] = a1.z; As[ak+3][ar+64] = a1.w;
        if (tid < 128) {
            const int br = tid >> 2;
            Bs[ak+0][br] = b0.x; Bs[ak+1][br] = b0.y; Bs[ak+2][br] = b0.z; Bs[ak+3][br] = b0.w;
        }
        __syncthreads();
        #pragma unroll
        for (int k = 0; k < 16; ++k) {
            float af[8];
            *(float4*)&af[0] = *(const float4*)&As[k][tr*8];
            *(float4*)&af[4] = *(const float4*)&As[k][tr*8+4];
            const float bf0 = Bs[k][tc*2], bf1 = Bs[k][tc*2+1];
            #pragma unroll
            for (int i = 0; i < 8; ++i) {
                acc[i][0] = fmaf(af[i], bf0, acc[i][0]);
                acc[i][1] = fmaf(af[i], bf1, acc[i][1]);
            }
        }
    }
    #pragma unroll
    for (int i = 0; i < 8; ++i) {
        atomicAdd(&C[(size_t)(bm + tr*8 + i) * EX + bn + tc*2 + 0], acc[i][0]);
        atomicAdd(&C[(size_t)(bm + tr*8 + i) * EX + bn + tc*2 + 1], acc[i][1]);
    }
}

// ---------------------------------------------------------------------------
// causal depthwise conv (d_conv=4) + SiLU
// ---------------------------------------------------------------------------
__global__ __launch_bounds__(256)
void conv_silu(const float* __restrict__ xz, const float* __restrict__ cw,
               const float* __restrict__ cb, float* __restrict__ xc)
{
    const int g   = blockIdx.x * 256 + threadIdx.x;
    const int nd4 = DI / 4;
    const int t   = g / nd4;
    const int d   = (g % nd4) * 4;
    const int l   = t & (L_ - 1);
    float w[4][4];
    #pragma unroll
    for (int c2 = 0; c2 < 4; ++c2) {
        float4 w4 = *(const float4*)(cw + (size_t)(d + c2) * 4);
        w[c2][0] = w4.x; w[c2][1] = w4.y; w[c2][2] = w4.z; w[c2][3] = w4.w;
    }
    float4 acc = *(const float4*)(cb + d);
    #pragma unroll
    for (int j = 0; j < 4; ++j) {
        const int lj = l + j - 3;
        if (lj >= 0) {
            const float4 x4 = *(const float4*)(xz + (size_t)(t + j - 3) * E2 + d);
            acc.x = fmaf(x4.x, w[0][j], acc.x);
            acc.y = fmaf(x4.y, w[1][j], acc.y);
            acc.z = fmaf(x4.z, w[2][j], acc.z);
            acc.w = fmaf(x4.w, w[3][j], acc.w);
        }
    }
    acc.x *= sigmoidf_(acc.x); acc.y *= sigmoidf_(acc.y);
    acc.z *= sigmoidf_(acc.z); acc.w *= sigmoidf_(acc.w);
    *(float4*)(xc + (size_t)t * DI + d) = acc;
}

// ---------------------------------------------------------------------------
// selective scan, (d,n)-parallel; fuses softplus, D*u, silu(z). grid 512
// ---------------------------------------------------------------------------
__global__ __launch_bounds__(256)
void scan_kernel(const float* __restrict__ u_in,   // xc  [T][DI]
                 const float* __restrict__ xdbl,   // [T][EX]
                 const float* __restrict__ draw,   // raw delta [T][DI]
                 const float* __restrict__ xz,     // [T][E2], z at col DI+d
                 const float* __restrict__ dt_bias,
                 const float* __restrict__ A_log,  // [DI][NS]
                 const float* __restrict__ Dvec,
                 float* __restrict__ y)            // [T][DI]
{
    __shared__ float sdt[64][16];
    __shared__ float su [64][16];
    __shared__ float sB [64][16];
    __shared__ float sC [64][16];
    __shared__ float sz [64][16];
    const int blk = blockIdx.x;
    const int b   = blk >> 8;
    const int d0  = (blk & 255) * 16;
    const int tid = threadIdx.x;
    const int ch  = tid >> 4;
    const int n   = tid & 15;
    const int d   = d0 + ch;
    const float a    = -__expf(A_log[(size_t)d * NS + n]);
    const float bias = dt_bias[d];
    const float Dd   = Dvec[d];
    const int li = tid >> 4;
    const int lc = tid & 15;
    float s = 0.f;
    for (int c = 0; c < L_ / 64; ++c) {
        const int t0 = b * L_ + c * 64;
        __syncthreads();
        #pragma unroll
        for (int p = 0; p < 4; ++p) {
            const int i = li + p * 16;
            const size_t trow = (size_t)(t0 + i);
            sdt[i][lc] = draw[trow * DI + d0 + lc];
            su [i][lc] = u_in[trow * DI + d0 + lc];
            sB [i][lc] = xdbl[trow * EX + RK + lc];
            sC [i][lc] = xdbl[trow * EX + RK + NS + lc];
            sz [i][lc] = xz  [trow * E2 + DI + d0 + lc];
        }
        __syncthreads();
        #pragma unroll 4
        for (int i = 0; i < 64; ++i) {
            const float x  = sdt[i][ch] + bias;
            const float dt = fmaxf(x, 0.f) + __logf(1.f + __expf(-fabsf(x)));
            const float u  = su[i][ch];
            const float dA = __expf(dt * a);
            s = fmaf(s, dA, dt * u * sB[i][n]);
            float pc = s * sC[i][n];
            pc += __shfl_xor(pc, 8);
            pc += __shfl_xor(pc, 4);
            pc += __shfl_xor(pc, 2);
            pc += __shfl_xor(pc, 1);
            if (n == 0) {
                const float zv = sz[i][ch];
                const float yv = (pc + Dd * u) * (zv * sigmoidf_(zv));
                y[(size_t)(t0 + i) * DI + d] = yv;
            }
        }
    }
}

// ---------------------------------------------------------------------------
// normalized FWHT over d_inner=4096 per token, fused bf16 hi/lo split output
// ---------------------------------------------------------------------------
__global__ __launch_bounds__(256)
void fwht_split(const float* __restrict__ y, unsigned short* __restrict__ h,
                unsigned short* __restrict__ l)
{
    __shared__ float ls[4096];
    const float* row = y + (size_t)blockIdx.x * DI;
    for (int i = threadIdx.x; i < 4096; i += 256) ls[i] = row[i];
    __syncthreads();
    for (int st = 0; st < 12; ++st) {
        const int stride = 1 << st;
        for (int k = threadIdx.x; k < 2048; k += 256) {
            const int i = ((k >> st) << (st + 1)) | (k & (stride - 1));
            const int j = i | stride;
            const float a = ls[i], b = ls[j];
            ls[i] = a + b; ls[j] = a - b;
        }
        __syncthreads();
    }
    const float sc = 1.0f / 64.0f;   // 1/sqrt(4096)
    const size_t base = (size_t)blockIdx.x * DI;
    for (int i = threadIdx.x; i < 4096; i += 256) {
        const float v = ls[i] * sc;
        const unsigned short hb = bf_rne(v);
        h[base + i] = hb;
        l[base + i] = bf_rne(v - bf_to_f(hb));
    }
}

// ---------------------------------------------------------------------------
extern "C" void kernel_launch(void* const* d_in, const int* in_sizes, int n_in,
                              void* d_out, int out_size, void* d_ws, size_t ws_size,
                              hipStream_t stream)
{
    const float* hidden  = (const float*)d_in[0];
    const float* W_in    = (const float*)d_in[1];
    const float* conv_w  = (const float*)d_in[2];
    const float* conv_b  = (const float*)d_in[3];
    const float* W_x     = (const float*)d_in[4];
    const float* W_dt    = (const float*)d_in[5];
    const float* dt_bias = (const float*)d_in[6];
    const float* A_log   = (const float*)d_in[7];
    const float* Dvec    = (const float*)d_in[8];
    const float* W_out   = (const float*)d_in[9];
    float* out = (float*)d_out;

    char* ws = (char*)d_ws;
    // fp32 intermediates
    float* xz   = (float*)(ws + MB(0));    // [T][E2]  64 MB   (live to scan)
    float* xc   = (float*)(ws + MB(64));   // [T][DI]  32 MB   (live to scan)
    float* xdbl = (float*)(ws + MB(96));   // [T][EX]   2 MB
    float* draw = (float*)(ws + MB(98));   // [T][DI]  32 MB   (written step 7)
    float* ybuf = (float*)(ws + MB(130));  // [T][DI]  32 MB   (written step 8)
    // bf16 hi/lo buffers (lifetime-packed)
    unsigned short* hh  = (unsigned short*)(ws + MB(162)); //  8 MB, dead after in_proj
    unsigned short* hl  = (unsigned short*)(ws + MB(170)); //  8 MB, dead after in_proj
    unsigned short* wih = (unsigned short*)(ws + MB(98));  // 32 MB, in draw slot (free until dt_proj)
    unsigned short* wil = (unsigned short*)(ws + MB(130)); // 32 MB, in ybuf slot (free until scan)
    unsigned short* xbh = (unsigned short*)(ws + MB(162)); // 0.7 MB, reuse hh
    unsigned short* xbl = (unsigned short*)(ws + MB(163));
    unsigned short* wdh = (unsigned short*)(ws + MB(164)); //  1 MB
    unsigned short* wdl = (unsigned short*)(ws + MB(165));
    unsigned short* woh = (unsigned short*)(ws + MB(166)); // 16 MB
    unsigned short* wol = (unsigned short*)(ws + MB(182)); // 16 MB (peak 198 MB)
    unsigned short* yh  = (unsigned short*)(ws + MB(0));   // 16 MB, reuse xz after scan
    unsigned short* yl  = (unsigned short*)(ws + MB(16));  // 16 MB

    const dim3 blk(256);

    // 1) fp32 -> bf16 hi/lo for in_proj operands
    split_bf16<<<dim3(4096),  blk, 0, stream>>>(hidden, hh, hl, T_ * DM / 4);
    split_bf16<<<dim3(16384), blk, 0, stream>>>(W_in, wih, wil, E2 * DM / 4);

    // 2) in_proj: xz[t][e] = hidden[t][:] . W_in[e][:]   (bf16x3 MFMA)
    gemm_bf16x3<<<dim3(E2/128, T_/128), blk, 0, stream>>>(hh, hl, wih, wil, xz, DM, DM, DM, E2);

    // 3) depthwise causal conv + SiLU -> xc
    conv_silu<<<dim3((T_ * (DI/4)) / 256), blk, 0, stream>>>(xz, conv_w, conv_b, xc);

    // 4) x_proj (fp32 split-K): xdbl[t][e] = xc[t][:] . W_x[e][:]
    hipMemsetAsync(xdbl, 0, (size_t)T_ * EX * sizeof(float), stream);
    gemm_xproj<<<dim3(5, 16, 8), blk, 0, stream>>>(xc, W_x, xdbl);

    // 5) dt_proj (bf16x3): draw[t][d] = xdbl[t][0:128] . W_dt[d][:]
    split_bf16<<<dim3(320), blk, 0, stream>>>(xdbl, xbh, xbl, T_ * EX / 4);
    split_bf16<<<dim3(512), blk, 0, stream>>>(W_dt, wdh, wdl, DI * RK / 4);
    gemm_bf16x3<<<dim3(DI/128, T_/128), blk, 0, stream>>>(xbh, xbl, wdh, wdl, draw, RK, EX, RK, DI);

    // 6) selective scan + D*u + silu(z) gate -> ybuf
    scan_kernel<<<dim3(512), blk, 0, stream>>>(xc, xdbl, draw, xz, dt_bias, A_log, Dvec, ybuf);

    // 7) out_proj operand prep
    split_bf16<<<dim3(8192), blk, 0, stream>>>(W_out, woh, wol, DM * DI / 4);
    fwht_split<<<dim3(T_), blk, 0, stream>>>(ybuf, yh, yl);

    // 8) out_proj (bf16x3) -> d_out
    gemm_bf16x3<<<dim3(DM/128, T_/128), blk, 0, stream>>>(yh, yl, woh, wol, out, DI, DI, DI, DM);
}

// Round 4
// 759.550 us; speedup vs baseline: 2.6517x; 1.3028x over previous
//
#include <hip/hip_runtime.h>

#define B_   2
#define L_   1024
#define T_   2048      // B_*L_
#define DM   2048
#define DI   4096
#define E2   8192
#define NS   16
#define RK   128
#define EX   160       // RK + 2*NS
#define SEG  16        // scan segments
#define SLEN (L_/SEG)  // 64 steps per segment
#define SLAB (B_*NS*DI)
#define MB(x) ((size_t)(x) << 20)

typedef __bf16 bf16x8 __attribute__((ext_vector_type(8)));
typedef float  f32x4  __attribute__((ext_vector_type(4)));

__device__ __forceinline__ float sigmoidf_(float x) { return 1.f / (1.f + __expf(-x)); }

__device__ __forceinline__ unsigned short bf_rne(float f) {
    unsigned int u = __float_as_uint(f);
    unsigned int r = u + 0x7fffu + ((u >> 16) & 1u);
    return (unsigned short)(r >> 16);
}
__device__ __forceinline__ float bf_to_f(unsigned short h) {
    return __uint_as_float(((unsigned int)h) << 16);
}
__device__ __forceinline__ float exp2_fast(float x) {
    float r;
    asm("v_exp_f32 %0, %1" : "=v"(r) : "v"(x));
    return r;
}

// ---------------------------------------------------------------------------
// fp32 -> bf16 hi/lo split (RNE both): x ~= hi + lo, rel err ~2^-18
// ---------------------------------------------------------------------------
__global__ __launch_bounds__(256)
void split_bf16(const float* __restrict__ x, unsigned short* __restrict__ h,
                unsigned short* __restrict__ l, int n4)
{
    const int i = blockIdx.x * 256 + threadIdx.x;
    if (i >= n4) return;
    const float4 v = ((const float4*)x)[i];
    ushort4 hv, lv;
    hv.x = bf_rne(v.x); lv.x = bf_rne(v.x - bf_to_f(hv.x));
    hv.y = bf_rne(v.y); lv.y = bf_rne(v.y - bf_to_f(hv.y));
    hv.z = bf_rne(v.z); lv.z = bf_rne(v.z - bf_to_f(hv.z));
    hv.w = bf_rne(v.w); lv.w = bf_rne(v.w - bf_to_f(hv.w));
    ((ushort4*)h)[i] = hv;
    ((ushort4*)l)[i] = lv;
}

// ---------------------------------------------------------------------------
// bf16x3 split-precision BT-GEMM (m97 structure, 128x128 tile, BK=32)
// ---------------------------------------------------------------------------
__global__ __launch_bounds__(256)
void gemm_bf16x3(const unsigned short* __restrict__ Ah, const unsigned short* __restrict__ Al,
                 const unsigned short* __restrict__ Bh, const unsigned short* __restrict__ Bl,
                 float* __restrict__ C, int K, int lda, int ldb, int ldc)
{
    __shared__ unsigned short lsAh[4096], lsAl[4096], lsBh[4096], lsBl[4096];
    const int bm   = blockIdx.y * 128;
    const int bn   = blockIdx.x * 128;
    const int tid  = threadIdx.x;
    const int lane = tid & 63;
    const int wv   = tid >> 6;
    const int wr   = (wv >> 1) * 64;
    const int wc   = (wv & 1) * 64;
    const int grow = lane >> 2;
    const int gcol = (lane & 3) * 8;
    const int fr   = lane & 15;
    const int fk   = (lane >> 4) * 8;

    f32x4 acc[4][4] = {};

    for (int k0 = 0; k0 < K; k0 += 32) {
        __syncthreads();
        #pragma unroll
        for (int is = 0; is < 2; ++is) {
            const int c = is * 4 + wv;
            const size_t ao = (size_t)(bm + c * 16 + grow) * lda + k0 + gcol;
            const size_t bo = (size_t)(bn + c * 16 + grow) * ldb + k0 + gcol;
            __builtin_amdgcn_global_load_lds((const __attribute__((address_space(1))) void*)(Ah + ao),
                (__attribute__((address_space(3))) void*)(lsAh + c * 512), 16, 0, 0);
            __builtin_amdgcn_global_load_lds((const __attribute__((address_space(1))) void*)(Al + ao),
                (__attribute__((address_space(3))) void*)(lsAl + c * 512), 16, 0, 0);
            __builtin_amdgcn_global_load_lds((const __attribute__((address_space(1))) void*)(Bh + bo),
                (__attribute__((address_space(3))) void*)(lsBh + c * 512), 16, 0, 0);
            __builtin_amdgcn_global_load_lds((const __attribute__((address_space(1))) void*)(Bl + bo),
                (__attribute__((address_space(3))) void*)(lsBl + c * 512), 16, 0, 0);
        }
        __syncthreads();

        bf16x8 ah[4], al[4], bh[4], bl[4];
        #pragma unroll
        for (int m = 0; m < 4; ++m) {
            const int ra = (wr + m * 16 + fr) * 32 + fk;
            ah[m] = *(const bf16x8*)(lsAh + ra);
            al[m] = *(const bf16x8*)(lsAl + ra);
        }
        #pragma unroll
        for (int n = 0; n < 4; ++n) {
            const int rb = (wc + n * 16 + fr) * 32 + fk;
            bh[n] = *(const bf16x8*)(lsBh + rb);
            bl[n] = *(const bf16x8*)(lsBl + rb);
        }
        #pragma unroll
        for (int m = 0; m < 4; ++m)
            #pragma unroll
            for (int n = 0; n < 4; ++n) {
                acc[m][n] = __builtin_amdgcn_mfma_f32_16x16x32_bf16(ah[m], bh[n], acc[m][n], 0, 0, 0);
                acc[m][n] = __builtin_amdgcn_mfma_f32_16x16x32_bf16(ah[m], bl[n], acc[m][n], 0, 0, 0);
                acc[m][n] = __builtin_amdgcn_mfma_f32_16x16x32_bf16(al[m], bh[n], acc[m][n], 0, 0, 0);
            }
    }

    #pragma unroll
    for (int m = 0; m < 4; ++m)
        #pragma unroll
        for (int n = 0; n < 4; ++n) {
            float* cp = C + (size_t)(bm + wr + m * 16 + (lane >> 4) * 4) * ldc
                          + bn + wc + n * 16 + fr;
            #pragma unroll
            for (int r = 0; r < 4; ++r) cp[(size_t)r * ldc] = acc[m][n][r];
        }
}

// ---------------------------------------------------------------------------
// x_proj (fp32, skinny N=160): split-K + atomicAdd. grid (5, 16, 8)
// ---------------------------------------------------------------------------
__global__ __launch_bounds__(256)
void gemm_xproj(const float* __restrict__ A, const float* __restrict__ B,
                float* __restrict__ C)
{
    __shared__ float As[16][132];
    __shared__ float Bs[16][36];
    const int bn    = blockIdx.x * 32;
    const int bm    = blockIdx.y * 128;
    const int kbase = blockIdx.z * 512;
    const int tid = threadIdx.x;
    const int tr  = tid >> 4;
    const int tc  = tid & 15;
    const int ar  = tid >> 2;
    const int ak  = (tid & 3) * 4;
    float acc[8][2] = {};
    for (int kc = 0; kc < 512; kc += 16) {
        const int k0 = kbase + kc;
        float4 a0 = *(const float4*)(A + (size_t)(bm + ar) * DI + k0 + ak);
        float4 a1 = *(const float4*)(A + (size_t)(bm + ar + 64) * DI + k0 + ak);
        float4 b0 = {0,0,0,0};
        if (tid < 128) b0 = *(const float4*)(B + (size_t)(bn + (tid >> 2)) * DI + k0 + ak);
        __syncthreads();
        As[ak+0][ar] = a0.x; As[ak+1][ar] = a0.y; As[ak+2][ar] = a0.z; As[ak+3][ar] = a0.w;
        As[ak+0][ar+64] = a1.x; As[ak+1][ar+64] = a1.y; As[ak+2][ar+64] = a1.z; As[ak+3][ar+64] = a1.w;
        if (tid < 128) {
            const int br = tid >> 2;
            Bs[ak+0][br] = b0.x; Bs[ak+1][br] = b0.y; Bs[ak+2][br] = b0.z; Bs[ak+3][br] = b0.w;
        }
        __syncthreads();
        #pragma unroll
        for (int k = 0; k < 16; ++k) {
            float af[8];
            *(float4*)&af[0] = *(const float4*)&As[k][tr*8];
            *(float4*)&af[4] = *(const float4*)&As[k][tr*8+4];
            const float bf0 = Bs[k][tc*2], bf1 = Bs[k][tc*2+1];
            #pragma unroll
            for (int i = 0; i < 8; ++i) {
                acc[i][0] = fmaf(af[i], bf0, acc[i][0]);
                acc[i][1] = fmaf(af[i], bf1, acc[i][1]);
            }
        }
    }
    #pragma unroll
    for (int i = 0; i < 8; ++i) {
        atomicAdd(&C[(size_t)(bm + tr*8 + i) * EX + bn + tc*2 + 0], acc[i][0]);
        atomicAdd(&C[(size_t)(bm + tr*8 + i) * EX + bn + tc*2 + 1], acc[i][1]);
    }
}

// ---------------------------------------------------------------------------
// causal depthwise conv (d_conv=4) + SiLU
// ---------------------------------------------------------------------------
__global__ __launch_bounds__(256)
void conv_silu(const float* __restrict__ xz, const float* __restrict__ cw,
               const float* __restrict__ cb, float* __restrict__ xc)
{
    const int g   = blockIdx.x * 256 + threadIdx.x;
    const int nd4 = DI / 4;
    const int t   = g / nd4;
    const int d   = (g % nd4) * 4;
    const int l   = t & (L_ - 1);
    float w[4][4];
    #pragma unroll
    for (int c2 = 0; c2 < 4; ++c2) {
        float4 w4 = *(const float4*)(cw + (size_t)(d + c2) * 4);
        w[c2][0] = w4.x; w[c2][1] = w4.y; w[c2][2] = w4.z; w[c2][3] = w4.w;
    }
    float4 acc = *(const float4*)(cb + d);
    #pragma unroll
    for (int j = 0; j < 4; ++j) {
        const int lj = l + j - 3;
        if (lj >= 0) {
            const float4 x4 = *(const float4*)(xz + (size_t)(t + j - 3) * E2 + d);
            acc.x = fmaf(x4.x, w[0][j], acc.x);
            acc.y = fmaf(x4.y, w[1][j], acc.y);
            acc.z = fmaf(x4.z, w[2][j], acc.z);
            acc.w = fmaf(x4.w, w[3][j], acc.w);
        }
    }
    acc.x *= sigmoidf_(acc.x); acc.y *= sigmoidf_(acc.y);
    acc.z *= sigmoidf_(acc.z); acc.w *= sigmoidf_(acc.w);
    *(float4*)(xc + (size_t)t * DI + d) = acc;
}

// ---------------------------------------------------------------------------
// Segmented scan, lane-owns-channel (16 states in registers per lane).
// passA: per (b, segment, channel): P[n] = prod(dA), S[n] = local scan from 0.
// Layout of pA/aB: [g][b][n][d]  (idx = g*SLAB + (b*NS+n)*DI + d)
// ---------------------------------------------------------------------------
__global__ __launch_bounds__(256)
void scan_passA(const float* __restrict__ u_in,   // xc  [T][DI]
                const float* __restrict__ xdbl,   // [T][EX]
                const float* __restrict__ draw,   // raw delta [T][DI]
                const float* __restrict__ dt_bias,
                const float* __restrict__ A_log,  // [DI][NS]
                float* __restrict__ pA, float* __restrict__ aB)
{
    __shared__ float sBl[SLEN * NS];
    const int d  = blockIdx.x * 256 + threadIdx.x;
    const int g  = blockIdx.y;
    const int b  = blockIdx.z;
    const int t0 = b * L_ + g * SLEN;

    for (int i = threadIdx.x; i < SLEN * NS; i += 256)
        sBl[i] = xdbl[(size_t)(t0 + (i >> 4)) * EX + RK + (i & 15)];
    __syncthreads();

    const float bias = dt_bias[d];
    float a2[NS], P[NS], S[NS];
    #pragma unroll
    for (int n = 0; n < NS; ++n) {
        a2[n] = -__expf(A_log[(size_t)d * NS + n]) * 1.44269504f;  // log2(e)
        P[n] = 1.f; S[n] = 0.f;
    }
    for (int t = 0; t < SLEN; ++t) {
        const float dtr = draw[(size_t)(t0 + t) * DI + d];
        const float uu  = u_in[(size_t)(t0 + t) * DI + d];
        const float xv  = dtr + bias;
        const float dt  = fmaxf(xv, 0.f) + __logf(1.f + __expf(-fabsf(xv)));
        const float dtu = dt * uu;
        #pragma unroll
        for (int n = 0; n < NS; ++n) {
            const float e = exp2_fast(dt * a2[n]);
            P[n] *= e;
            S[n] = fmaf(S[n], e, dtu * sBl[(t << 4) | n]);
        }
    }
    const size_t base = (size_t)g * SLAB + (size_t)b * NS * DI + d;
    #pragma unroll
    for (int n = 0; n < NS; ++n) {
        pA[base + (size_t)n * DI] = P[n];
        aB[base + (size_t)n * DI] = S[n];
    }
}

// combine: aB[g] becomes cumulative state at END of segment g. grid 512x256.
__global__ __launch_bounds__(256)
void scan_combine(const float* __restrict__ pA, float* __restrict__ aB)
{
    const int j = blockIdx.x * 256 + threadIdx.x;   // within-slab offset
    float cum = aB[j];
    #pragma unroll
    for (int g = 1; g < SEG; ++g) {
        const size_t idx = (size_t)g * SLAB + j;
        cum = fmaf(pA[idx], cum, aB[idx]);
        aB[idx] = cum;
    }
}

// passB: re-run each segment from exact boundary state; fuse y, D*u, silu(z).
__global__ __launch_bounds__(256)
void scan_passB(const float* __restrict__ u_in,   // xc  [T][DI]
                const float* __restrict__ xdbl,   // [T][EX]
                const float* __restrict__ draw,   // [T][DI]
                const float* __restrict__ xz,     // [T][E2], z at DI+d
                const float* __restrict__ dt_bias,
                const float* __restrict__ A_log,
                const float* __restrict__ Dvec,
                const float* __restrict__ aB,     // cumulative boundary states
                float* __restrict__ y)            // [T][DI]
{
    __shared__ float sBl[SLEN * NS];
    __shared__ float sCl[SLEN * NS];
    const int d  = blockIdx.x * 256 + threadIdx.x;
    const int g  = blockIdx.y;
    const int b  = blockIdx.z;
    const int t0 = b * L_ + g * SLEN;

    for (int i = threadIdx.x; i < SLEN * NS; i += 256) {
        const size_t row = (size_t)(t0 + (i >> 4)) * EX + RK + (i & 15);
        sBl[i] = xdbl[row];
        sCl[i] = xdbl[row + NS];
    }
    __syncthreads();

    const float bias = dt_bias[d];
    const float Dd   = Dvec[d];
    float a2[NS], S[NS];
    #pragma unroll
    for (int n = 0; n < NS; ++n)
        a2[n] = -__expf(A_log[(size_t)d * NS + n]) * 1.44269504f;
    if (g == 0) {
        #pragma unroll
        for (int n = 0; n < NS; ++n) S[n] = 0.f;
    } else {
        const size_t base = (size_t)(g - 1) * SLAB + (size_t)b * NS * DI + d;
        #pragma unroll
        for (int n = 0; n < NS; ++n) S[n] = aB[base + (size_t)n * DI];
    }
    for (int t = 0; t < SLEN; ++t) {
        const float dtr = draw[(size_t)(t0 + t) * DI + d];
        const float uu  = u_in[(size_t)(t0 + t) * DI + d];
        const float zv  = xz  [(size_t)(t0 + t) * E2 + DI + d];
        const float xv  = dtr + bias;
        const float dt  = fmaxf(xv, 0.f) + __logf(1.f + __expf(-fabsf(xv)));
        const float dtu = dt * uu;
        float yv = 0.f;
        #pragma unroll
        for (int n = 0; n < NS; ++n) {
            const float e = exp2_fast(dt * a2[n]);
            S[n] = fmaf(S[n], e, dtu * sBl[(t << 4) | n]);
            yv   = fmaf(S[n], sCl[(t << 4) | n], yv);
        }
        yv = (yv + Dd * uu) * (zv * sigmoidf_(zv));
        y[(size_t)(t0 + t) * DI + d] = yv;
    }
}

// ---------------------------------------------------------------------------
// normalized FWHT over d_inner=4096 per token, fused bf16 hi/lo split output
// ---------------------------------------------------------------------------
__global__ __launch_bounds__(256)
void fwht_split(const float* __restrict__ y, unsigned short* __restrict__ h,
                unsigned short* __restrict__ l)
{
    __shared__ float ls[4096];
    const float* row = y + (size_t)blockIdx.x * DI;
    for (int i = threadIdx.x; i < 4096; i += 256) ls[i] = row[i];
    __syncthreads();
    for (int st = 0; st < 12; ++st) {
        const int stride = 1 << st;
        for (int k = threadIdx.x; k < 2048; k += 256) {
            const int i = ((k >> st) << (st + 1)) | (k & (stride - 1));
            const int j = i | stride;
            const float a = ls[i], b = ls[j];
            ls[i] = a + b; ls[j] = a - b;
        }
        __syncthreads();
    }
    const float sc = 1.0f / 64.0f;   // 1/sqrt(4096)
    const size_t base = (size_t)blockIdx.x * DI;
    for (int i = threadIdx.x; i < 4096; i += 256) {
        const float v = ls[i] * sc;
        const unsigned short hb = bf_rne(v);
        h[base + i] = hb;
        l[base + i] = bf_rne(v - bf_to_f(hb));
    }
}

// ---------------------------------------------------------------------------
extern "C" void kernel_launch(void* const* d_in, const int* in_sizes, int n_in,
                              void* d_out, int out_size, void* d_ws, size_t ws_size,
                              hipStream_t stream)
{
    const float* hidden  = (const float*)d_in[0];
    const float* W_in    = (const float*)d_in[1];
    const float* conv_w  = (const float*)d_in[2];
    const float* conv_b  = (const float*)d_in[3];
    const float* W_x     = (const float*)d_in[4];
    const float* W_dt    = (const float*)d_in[5];
    const float* dt_bias = (const float*)d_in[6];
    const float* A_log   = (const float*)d_in[7];
    const float* Dvec    = (const float*)d_in[8];
    const float* W_out   = (const float*)d_in[9];
    float* out = (float*)d_out;

    char* ws = (char*)d_ws;
    // fp32 intermediates
    float* xz   = (float*)(ws + MB(0));    // [T][E2]  64 MB   (live to scan)
    float* xc   = (float*)(ws + MB(64));   // [T][DI]  32 MB   (live to scan)
    float* xdbl = (float*)(ws + MB(96));   // [T][EX]   2 MB
    float* draw = (float*)(ws + MB(98));   // [T][DI]  32 MB
    float* ybuf = (float*)(ws + MB(130));  // [T][DI]  32 MB
    // bf16 hi/lo buffers (lifetime-packed)
    unsigned short* hh  = (unsigned short*)(ws + MB(162)); //  8 MB, dead after in_proj
    unsigned short* hl  = (unsigned short*)(ws + MB(170)); //  8 MB, dead after in_proj
    unsigned short* wih = (unsigned short*)(ws + MB(98));  // 32 MB (draw slot, free until dt_proj)
    unsigned short* wil = (unsigned short*)(ws + MB(130)); // 32 MB (ybuf slot, free until scan)
    unsigned short* xbh = (unsigned short*)(ws + MB(162)); // 0.7 MB (reuse hh)
    unsigned short* xbl = (unsigned short*)(ws + MB(163));
    unsigned short* wdh = (unsigned short*)(ws + MB(164)); //  1 MB
    unsigned short* wdl = (unsigned short*)(ws + MB(165));
    // scan boundary states: live only during step 6 (before woh/wol are written)
    float* pA = (float*)(ws + MB(166));    // SEG*SLAB*4 = 8.4 MB
    float* aB = (float*)(ws + MB(176));    // 8.4 MB
    unsigned short* woh = (unsigned short*)(ws + MB(166)); // 16 MB (after scan)
    unsigned short* wol = (unsigned short*)(ws + MB(182)); // 16 MB (peak 198 MB)
    unsigned short* yh  = (unsigned short*)(ws + MB(0));   // 16 MB (xz slot, after scan)
    unsigned short* yl  = (unsigned short*)(ws + MB(16));  // 16 MB

    const dim3 blk(256);

    // 1) fp32 -> bf16 hi/lo for in_proj operands
    split_bf16<<<dim3(4096),  blk, 0, stream>>>(hidden, hh, hl, T_ * DM / 4);
    split_bf16<<<dim3(16384), blk, 0, stream>>>(W_in, wih, wil, E2 * DM / 4);

    // 2) in_proj: xz[t][e] = hidden[t][:] . W_in[e][:]   (bf16x3 MFMA)
    gemm_bf16x3<<<dim3(E2/128, T_/128), blk, 0, stream>>>(hh, hl, wih, wil, xz, DM, DM, DM, E2);

    // 3) depthwise causal conv + SiLU -> xc
    conv_silu<<<dim3((T_ * (DI/4)) / 256), blk, 0, stream>>>(xz, conv_w, conv_b, xc);

    // 4) x_proj (fp32 split-K): xdbl[t][e] = xc[t][:] . W_x[e][:]
    hipMemsetAsync(xdbl, 0, (size_t)T_ * EX * sizeof(float), stream);
    gemm_xproj<<<dim3(5, 16, 8), blk, 0, stream>>>(xc, W_x, xdbl);

    // 5) dt_proj (bf16x3): draw[t][d] = xdbl[t][0:128] . W_dt[d][:]
    split_bf16<<<dim3(320), blk, 0, stream>>>(xdbl, xbh, xbl, T_ * EX / 4);
    split_bf16<<<dim3(512), blk, 0, stream>>>(W_dt, wdh, wdl, DI * RK / 4);
    gemm_bf16x3<<<dim3(DI/128, T_/128), blk, 0, stream>>>(xbh, xbl, wdh, wdl, draw, RK, EX, RK, DI);

    // 6) segmented selective scan + D*u + silu(z) gate -> ybuf
    scan_passA<<<dim3(DI/256, SEG, B_), blk, 0, stream>>>(xc, xdbl, draw, dt_bias, A_log, pA, aB);
    scan_combine<<<dim3(SLAB/256), blk, 0, stream>>>(pA, aB);
    scan_passB<<<dim3(DI/256, SEG, B_), blk, 0, stream>>>(xc, xdbl, draw, xz, dt_bias, A_log,
                                                          Dvec, aB, ybuf);

    // 7) out_proj operand prep
    split_bf16<<<dim3(8192), blk, 0, stream>>>(W_out, woh, wol, DM * DI / 4);
    fwht_split<<<dim3(T_), blk, 0, stream>>>(ybuf, yh, yl);

    // 8) out_proj (bf16x3) -> d_out
    gemm_bf16x3<<<dim3(DM/128, T_/128), blk, 0, stream>>>(yh, yl, woh, wol, out, DI, DI, DI, DM);
}